// Round 8
// baseline (185.350 us; speedup 1.0000x reference)
//
#include <hip/hip_runtime.h>
#include <math.h>

#define M_TOTAL (32 * 8732)        // 279424 anchors
#define M4      (M_TOTAL / 4)      // 69856 float4
#define NBLK_A  ((M_TOTAL + 255) / 256)   // 1092 blocks, thread-per-anchor
#define NBLK_S  273                // ceil(M4 / 256)
#define NREP    16                 // level-0 hist replication

// ---- workspace layout (bytes), all 16B-aligned ----
#define CON_B    ((size_t)0)                          // M floats
#define HISTR_B  ((size_t)M_TOTAL * 4)                // NREP*2048 u32
#define H1_B     (HISTR_B + (size_t)NREP * 2048 * 4)  // 2048 u32
#define H2_B     (H1_B + (size_t)2048 * 4)            // 1024 u32
#define G_B      (H2_B + (size_t)1024 * 4)            // GS (128 B reserved)
#define PART_B   (G_B + 128)                          // NBLK_A float4 (fully written by kA)
#define ZERO_BYTES ((size_t)NREP * 2048 * 4 + 2048 * 4 + 1024 * 4 + 128)

struct GS {
    unsigned pn;      // written by kC block 0
    float    lossl;
    float    poslc;
    unsigned b0;
    unsigned k1;
    unsigned pref;    // written by kD block 0: (b0<<11)|b1
    unsigned k2;
    float    sumhi0;  // atomic: sum of con where (u>>21)  > b0
    float    sumhi1;  // atomic: sum where (u>>21)==b0 && mid > b1
};

// 4-byte-aligned float4 (rows are 324 B = 81 floats; only every 4th row is 16B-aligned;
// gfx950 supports dword-aligned dwordx4)
struct __attribute__((packed, aligned(4))) f4u { float x, y, z, w; };

__device__ __forceinline__ float smooth_l1(float d) {
    float ad = fabsf(d);
    return (ad < 1.0f) ? 0.5f * ad * ad : ad - 0.5f;
}

// 256-thread suffix-select over nbins (multiple of 256): finds bin with
// suffix(bin) >= k > suffix(bin+1); (k==0 -> bin=0,k=0). Verified R3-R7.
__device__ void selectk256(const unsigned* cnt, int nbins, unsigned k,
                           unsigned* ssum, unsigned* pbin, unsigned* pk) {
    const int t = threadIdx.x;
    const int chunk = nbins >> 8;
    if (t == 0) { *pbin = 0u; *pk = 0u; }
    unsigned tot = 0;
    for (int j = 0; j < chunk; ++j) tot += cnt[t * chunk + j];
    ssum[t] = tot;
    __syncthreads();
    for (int off = 1; off < 256; off <<= 1) {
        const unsigned val = ssum[t];
        const unsigned add = (t + off < 256) ? ssum[t + off] : 0u;
        __syncthreads();
        ssum[t] = val + add;
        __syncthreads();
    }
    const unsigned s_after = (t < 255) ? ssum[t + 1] : 0u;
    if (k > 0u && ssum[t] >= k && k > s_after) {
        unsigned cum = s_after;
        for (int j = chunk - 1; j >= 0; --j) {
            const unsigned bin = t * chunk + j;
            const unsigned nc = cum + cnt[bin];
            if (nc >= k) { *pbin = bin; *pk = k - cum; break; }
            cum = nc;
        }
    }
    __syncthreads();
}

// ---- kA: thread-per-anchor CE + smoothL1 + con_neg + hist + partials ----
__global__ __launch_bounds__(256) void kA(const float* __restrict__ ploc,
                                          const float* __restrict__ plabel,
                                          const float* __restrict__ gloc,
                                          const int* __restrict__ glabel,
                                          float* __restrict__ con,
                                          unsigned* __restrict__ histR,
                                          float4* __restrict__ part) {
    __shared__ unsigned lh[2048];
    __shared__ float    rf[4][3];

    const int tid  = threadIdx.x;
    const int lane = tid & 63;
    const int w    = tid >> 6;
    const int row  = blockIdx.x * 256 + tid;
    const bool live = row < M_TOTAL;

    for (int i = tid; i < 2048; i += 256) lh[i] = 0u;
    __syncthreads();

    float wl = 0.f, wc = 0.f, wp = 0.f;
    if (live) {
        // coalesced float4 per thread (ploc/gloc are [row][4], 16B-aligned)
        const float4 pl = ((const float4*)ploc)[row];
        const float4 gl = ((const float4*)gloc)[row];
        const int    gt = glabel[row];
        const int  mask = gt > 0;

        const float s = smooth_l1(pl.x - gl.x) + smooth_l1(pl.y - gl.y) +
                        smooth_l1(pl.z - gl.z) + smooth_l1(pl.w - gl.w);

        // 81 logits: 20 independent dwordx4 + 1 scalar, all in registers
        const float* rb = plabel + (size_t)row * 81;
        f4u v[20];
#pragma unroll
        for (int j = 0; j < 20; ++j) v[j] = ((const f4u*)rb)[j];
        const float v80 = rb[80];

        float m = v80;
#pragma unroll
        for (int j = 0; j < 20; ++j) {
            m = fmaxf(m, fmaxf(fmaxf(v[j].x, v[j].y), fmaxf(v[j].z, v[j].w)));
        }
        float e = __expf(v80 - m);
#pragma unroll
        for (int j = 0; j < 20; ++j) {
            e += __expf(v[j].x - m) + __expf(v[j].y - m) +
                 __expf(v[j].z - m) + __expf(v[j].w - m);
        }
        const float lse = m + __logf(e);

        const float x_gt   = rb[gt];          // L1-hot reload
        const float loss_c = lse - x_gt;
        const float cn     = mask ? 0.0f : fmaxf(loss_c, 0.0f);
        con[row] = cn;                        // coalesced dword store
        atomicAdd(&lh[__float_as_uint(cn) >> 21], 1u);
        if (mask) { wl = s; wc = loss_c; wp = 1.0f; }
    }

    // block-reduce the 3 scalars
#pragma unroll
    for (int off = 1; off < 64; off <<= 1) {
        wl += __shfl_xor(wl, off);
        wc += __shfl_xor(wc, off);
        wp += __shfl_xor(wp, off);
    }
    if (lane == 0) { rf[w][0] = wl; rf[w][1] = wc; rf[w][2] = wp; }
    __syncthreads();   // rf visible + lh atomics complete

    if (tid == 0)      // plain store, no contended atomics
        part[blockIdx.x] = make_float4(rf[0][0] + rf[1][0] + rf[2][0] + rf[3][0],
                                       rf[0][1] + rf[1][1] + rf[2][1] + rf[3][1],
                                       rf[0][2] + rf[1][2] + rf[2][2] + rf[3][2], 0.f);

    // merge private hist into replicated global hist (~13 nonzero bins/block)
    unsigned* hrep = histR + (size_t)(blockIdx.x & (NREP - 1)) * 2048;
    for (int i = tid; i < 2048; i += 256) {
        const unsigned c = lh[i];
        if (c) atomicAdd(&hrep[i], c);
    }
}

// ---- kC: every block redundantly folds histR+part + select0, then filters ----
__global__ __launch_bounds__(256) void kC(const float4* __restrict__ con4,
                                          const unsigned* __restrict__ histR,
                                          const float4* __restrict__ part,
                                          unsigned* __restrict__ h1,
                                          GS* __restrict__ G) {
    __shared__ unsigned lh[2048];
    __shared__ unsigned ssum[256];
    __shared__ unsigned sbin, sk;
    __shared__ float    wred[4];
    __shared__ float    rf3[4][3];
    const int tid = threadIdx.x;

    // fold hist replicas (cross-kernel plain cached loads, L2-hot)
    for (int b = tid; b < 2048; b += 256) {
        unsigned c = 0;
#pragma unroll
        for (int r = 0; r < NREP; ++r) c += histR[r * 2048 + b];
        lh[b] = c;
    }
    // redundant deterministic part[] reduce -> identical pn in every block
    float sl = 0.f, sc = 0.f, sp = 0.f;
    for (int p = tid; p < NBLK_A; p += 256) {
        const float4 q = part[p];
        sl += q.x; sc += q.y; sp += q.z;
    }
#pragma unroll
    for (int off = 1; off < 64; off <<= 1) {
        sl += __shfl_xor(sl, off); sc += __shfl_xor(sc, off); sp += __shfl_xor(sp, off);
    }
    if ((tid & 63) == 0) { rf3[tid >> 6][0] = sl; rf3[tid >> 6][1] = sc; rf3[tid >> 6][2] = sp; }
    __syncthreads();
    const float tsp = rf3[0][2] + rf3[1][2] + rf3[2][2] + rf3[3][2];
    const unsigned pn = (unsigned)(tsp + 0.5f);   // exact: integer-valued, < 2^24
    unsigned k0 = 3u * pn;
    if (k0 > (unsigned)M_TOTAL) k0 = (unsigned)M_TOTAL;

    selectk256(lh, 2048, k0, ssum, &sbin, &sk);
    const unsigned b0 = sbin, k1loc = sk;

    const int i = blockIdx.x * 256 + tid;
    float s = 0.f;
    if (i < M4) {
        const float4 q = con4[i];
        const float xs[4] = {q.x, q.y, q.z, q.w};
#pragma unroll
        for (int j = 0; j < 4; ++j) {
            const unsigned u  = __float_as_uint(xs[j]);
            const unsigned hi = u >> 21;
            if (hi > b0) s += xs[j];
            else if (hi == b0) atomicAdd(&h1[(u >> 10) & 0x7FFu], 1u);
        }
    }
#pragma unroll
    for (int off = 1; off < 64; off <<= 1) s += __shfl_xor(s, off);
    if ((tid & 63) == 0) wred[tid >> 6] = s;
    __syncthreads();
    if (tid == 0) {
        const float tot = wred[0] + wred[1] + wred[2] + wred[3];
        if (tot != 0.f) atomicAdd(&G->sumhi0, tot);
        if (blockIdx.x == 0) {
            G->pn = pn;
            G->lossl = rf3[0][0] + rf3[1][0] + rf3[2][0] + rf3[3][0];
            G->poslc = rf3[0][1] + rf3[1][1] + rf3[2][1] + rf3[3][1];
            G->b0 = b0; G->k1 = k1loc;
        }
    }
}

// ---- kD: every block redundantly selects level 1 from h1, then filters ----
__global__ __launch_bounds__(256) void kD(const float4* __restrict__ con4,
                                          const unsigned* __restrict__ h1,
                                          unsigned* __restrict__ h2,
                                          GS* __restrict__ G) {
    __shared__ unsigned lh[2048];
    __shared__ unsigned ssum[256];
    __shared__ unsigned sbin, sk;
    __shared__ float    wred[4];
    const int tid = threadIdx.x;

    for (int b = tid; b < 2048; b += 256) lh[b] = h1[b];   // 8 KB, L2-hot
    __syncthreads();

    const unsigned b0 = G->b0;   // cross-kernel (kC block 0)
    const unsigned k1 = G->k1;
    selectk256(lh, 2048, k1, ssum, &sbin, &sk);
    const unsigned b1 = sbin, k2loc = sk;

    const int i = blockIdx.x * 256 + tid;
    float s = 0.f;
    if (i < M4) {
        const float4 q = con4[i];
        const float xs[4] = {q.x, q.y, q.z, q.w};
#pragma unroll
        for (int j = 0; j < 4; ++j) {
            const unsigned u = __float_as_uint(xs[j]);
            if ((u >> 21) == b0) {
                const unsigned mid = (u >> 10) & 0x7FFu;
                if (mid > b1) s += xs[j];
                else if (mid == b1) atomicAdd(&h2[u & 0x3FFu], 1u);
            }
        }
    }
#pragma unroll
    for (int off = 1; off < 64; off <<= 1) s += __shfl_xor(s, off);
    if ((tid & 63) == 0) wred[tid >> 6] = s;
    __syncthreads();
    if (tid == 0) {
        const float tot = wred[0] + wred[1] + wred[2] + wred[3];
        if (tot != 0.f) atomicAdd(&G->sumhi1, tot);
        if (blockIdx.x == 0) { G->pref = (b0 << 11) | b1; G->k2 = k2loc; }
    }
}

// ---- kE: single tiny block — final select over h2 + output ----
__global__ __launch_bounds__(256) void kE(const unsigned* __restrict__ h2,
                                          const GS* __restrict__ G,
                                          float* __restrict__ out) {
    __shared__ unsigned lh[1024];
    __shared__ unsigned ssum[256];
    __shared__ unsigned sbin, sk;
    __shared__ float    wred[4];
    const int tid = threadIdx.x;

    for (int b = tid; b < 1024; b += 256) lh[b] = h2[b];
    __syncthreads();
    const unsigned pref = G->pref;
    const unsigned k2   = G->k2;
    selectk256(lh, 1024, k2, ssum, &sbin, &sk);
    const unsigned ct = sbin, r = sk;

    float s2 = 0.f;
    for (int b = tid; b < 1024; b += 256) {
        const unsigned c = lh[b];
        if ((unsigned)b > ct && c)
            s2 += (float)c * __uint_as_float((pref << 10) | (unsigned)b);
    }
#pragma unroll
    for (int off = 1; off < 64; off <<= 1) s2 += __shfl_xor(s2, off);
    if ((tid & 63) == 0) wred[tid >> 6] = s2;
    __syncthreads();

    if (tid == 0) {
        const float sumhi2 = wred[0] + wred[1] + wred[2] + wred[3];
        const unsigned pn = G->pn;
        float outv = 0.f;
        if (pn > 0u) {
            const float tval  = __uint_as_float((pref << 10) | ct);
            const float closs = G->poslc + G->sumhi0 + G->sumhi1 + sumhi2 + (float)r * tval;
            outv = (G->lossl + closs) / (float)pn;
        }
        out[0] = outv;
    }
}

extern "C" void kernel_launch(void* const* d_in, const int* in_sizes, int n_in,
                              void* d_out, int out_size, void* d_ws, size_t ws_size,
                              hipStream_t stream) {
    const float* ploc   = (const float*)d_in[0];
    const float* plabel = (const float*)d_in[1];
    const float* gloc   = (const float*)d_in[2];
    const int*   glabel = (const int*)d_in[3];
    float* out = (float*)d_out;
    char*  ws  = (char*)d_ws;

    float*    con   = (float*)(ws + CON_B);
    unsigned* histR = (unsigned*)(ws + HISTR_B);
    unsigned* h1    = (unsigned*)(ws + H1_B);
    unsigned* h2    = (unsigned*)(ws + H2_B);
    GS*       G     = (GS*)(ws + G_B);
    float4*   part  = (float4*)(ws + PART_B);

    hipMemsetAsync(ws + HISTR_B, 0, ZERO_BYTES, stream);   // histR + h1 + h2 + G (143 KB)
    kA<<<NBLK_A, 256, 0, stream>>>(ploc, plabel, gloc, glabel, con, histR, part);
    kC<<<NBLK_S, 256, 0, stream>>>((const float4*)con, histR, part, h1, G);
    kD<<<NBLK_S, 256, 0, stream>>>((const float4*)con, h1, h2, G);
    kE<<<1, 256, 0, stream>>>(h2, G, out);
}

// Round 9
// 169.943 us; speedup vs baseline: 1.0907x; 1.0907x over previous
//
#include <hip/hip_runtime.h>
#include <math.h>

#define M_TOTAL (32 * 8732)        // 279424 anchors
#define M4      (M_TOTAL / 4)      // 69856 float4
#define NBLK_A  (M_TOTAL / 64)     // 4366 blocks, 64 anchors each (R7 structure)
#define NBLK_S  273                // ceil(M4 / 256)
#define NREP    4                  // level-0 hist replication
#define NSC     16                 // scalar-partial replication

// ---- workspace layout (bytes), all 16B-aligned ----
#define CON_B    ((size_t)0)                          // M floats
#define HISTR_B  ((size_t)M_TOTAL * 4)                // NREP*2048 u32
#define H1_B     (HISTR_B + (size_t)NREP * 2048 * 4)  // 2048 u32
#define H2_B     (H1_B + (size_t)2048 * 4)            // 1024 u32
#define G_B      (H2_B + (size_t)1024 * 4)            // GS (128 B reserved)
#define SCAL_B   (G_B + 128)                          // NSC * 64 B replicated scalars
#define ZERO_BYTES ((size_t)NREP * 2048 * 4 + 2048 * 4 + 1024 * 4 + 128 + (size_t)NSC * 64)

struct GS {
    unsigned pn;      // written by kC block 0
    float    lossl;
    float    poslc;
    unsigned b0;
    unsigned k1;
    unsigned pref;    // written by kD block 0: (b0<<11)|b1
    unsigned k2;
    float    sumhi0;  // atomic: sum of con where (u>>21)  > b0
    float    sumhi1;  // atomic: sum where (u>>21)==b0 && mid > b1
};

struct __attribute__((aligned(64))) ScalRep {
    unsigned pn;
    float    lossl;
    float    poslc;
    unsigned pad[13];   // one 64B line per replica: no cross-replica line contention
};

__device__ __forceinline__ float smooth_l1(float d) {
    float ad = fabsf(d);
    return (ad < 1.0f) ? 0.5f * ad * ad : ad - 0.5f;
}

#define GLLDS16(gp, lp) __builtin_amdgcn_global_load_lds( \
    (__attribute__((address_space(1))) void*)(gp),        \
    (__attribute__((address_space(3))) void*)(lp), 16, 0, 0)

// 256-thread suffix-select over nbins (multiple of 256): finds bin with
// suffix(bin) >= k > suffix(bin+1); (k==0 -> bin=0,k=0). Verified R3-R8.
__device__ void selectk256(const unsigned* cnt, int nbins, unsigned k,
                           unsigned* ssum, unsigned* pbin, unsigned* pk) {
    const int t = threadIdx.x;
    const int chunk = nbins >> 8;
    if (t == 0) { *pbin = 0u; *pk = 0u; }
    unsigned tot = 0;
    for (int j = 0; j < chunk; ++j) tot += cnt[t * chunk + j];
    ssum[t] = tot;
    __syncthreads();
    for (int off = 1; off < 256; off <<= 1) {
        const unsigned val = ssum[t];
        const unsigned add = (t + off < 256) ? ssum[t + off] : 0u;
        __syncthreads();
        ssum[t] = val + add;
        __syncthreads();
    }
    const unsigned s_after = (t < 255) ? ssum[t + 1] : 0u;
    if (k > 0u && ssum[t] >= k && k > s_after) {
        unsigned cum = s_after;
        for (int j = chunk - 1; j >= 0; --j) {
            const unsigned bin = t * chunk + j;
            const unsigned nc = cum + cnt[bin];
            if (nc >= k) { *pbin = bin; *pk = k - cum; break; }
            cum = nc;
        }
    }
    __syncthreads();
}

// ---- kA: R7 structure — LDS-staged CE + smoothL1 + con_neg + hist + scalars ----
__global__ __launch_bounds__(256) void kA(const float* __restrict__ ploc,
                                          const float* __restrict__ plabel,
                                          const float* __restrict__ gloc,
                                          const int* __restrict__ glabel,
                                          float* __restrict__ con,
                                          unsigned* __restrict__ histR,
                                          ScalRep* __restrict__ scal) {
    __shared__ __align__(16) float stage[4 * 1296];  // 4 waves * 16 rows * 81 floats
    __shared__ unsigned lh[2048];
    __shared__ float rf[4][3];

    const int tid  = threadIdx.x;
    const int w    = tid >> 6;
    const int lane = tid & 63;
    const int g    = lane >> 2;
    const int l    = lane & 3;

    for (int i = tid; i < 2048; i += 256) lh[i] = 0u;

    const size_t wrow0 = (size_t)blockIdx.x * 64 + (size_t)w * 16;
    const char*  gsrc  = (const char*)(plabel + wrow0 * 81);
    char*        ldst  = (char*)&stage[w * 1296];
#pragma unroll
    for (int j = 0; j < 5; ++j)
        GLLDS16(gsrc + (size_t)j * 1024 + (size_t)lane * 16, ldst + j * 1024);
    if (lane < 4)
        GLLDS16(gsrc + 5120 + (size_t)lane * 16, ldst + 5120);

    const size_t row = wrow0 + g;
    const float pl = ploc[wrow0 * 4 + lane];
    const float gl = gloc[wrow0 * 4 + lane];
    int gt = 0;
    if (l == 0) gt = glabel[row];
    const int mask = gt > 0;

    float s = smooth_l1(pl - gl);
    s += __shfl_xor(s, 1);
    s += __shfl_xor(s, 2);

    __syncthreads();   // drains global_load_lds (vmcnt) + lh zero visible

    const float* rowp = &stage[w * 1296 + g * 81];
    float v[20];
    float m = -INFINITY;
#pragma unroll
    for (int j = 0; j < 20; ++j) { v[j] = rowp[j * 4 + l]; m = fmaxf(m, v[j]); }
    float v80 = 0.0f;
    if (l == 0) { v80 = rowp[80]; m = fmaxf(m, v80); }
    m = fmaxf(m, __shfl_xor(m, 1));
    m = fmaxf(m, __shfl_xor(m, 2));

    float e = 0.0f;
#pragma unroll
    for (int j = 0; j < 20; ++j) e += __expf(v[j] - m);
    if (l == 0) e += __expf(v80 - m);
    e += __shfl_xor(e, 1);
    e += __shfl_xor(e, 2);
    const float lse = m + __logf(e);

    float wl = 0.f, wc = 0.f, wp = 0.f;
    if (l == 0) {
        const float x_gt   = rowp[gt];
        const float loss_c = lse - x_gt;
        const float cn     = mask ? 0.0f : fmaxf(loss_c, 0.0f);
        con[row] = cn;
        atomicAdd(&lh[__float_as_uint(cn) >> 21], 1u);   // LDS atomic, cheap
        if (mask) { wl = s; wc = loss_c; wp = 1.0f; }
    }
#pragma unroll
    for (int off = 4; off < 64; off <<= 1) {
        wl += __shfl_xor(wl, off);
        wc += __shfl_xor(wc, off);
        wp += __shfl_xor(wp, off);
    }
    if (lane == 0) { rf[w][0] = wl; rf[w][1] = wc; rf[w][2] = wp; }
    __syncthreads();   // lh atomics done; rf visible

    if (tid == 0) {
        const float bl = rf[0][0] + rf[1][0] + rf[2][0] + rf[3][0];
        const float bc = rf[0][1] + rf[1][1] + rf[2][1] + rf[3][1];
        const unsigned bp = (unsigned)(rf[0][2] + rf[1][2] + rf[2][2] + rf[3][2] + 0.5f);
        ScalRep* sr = &scal[blockIdx.x & (NSC - 1)];
        if (bp) {                     // ~58% of blocks have 0 positives: skip
            atomicAdd(&sr->pn, bp);
            atomicAdd(&sr->lossl, bl);
            atomicAdd(&sr->poslc, bc);
        }
    }

    // merge private hist into replicated global hist (~6-10 nonzero bins/block)
    unsigned* hrep = histR + (size_t)(blockIdx.x & (NREP - 1)) * 2048;
    for (int i = tid; i < 2048; i += 256) {
        const unsigned c = lh[i];
        if (c) atomicAdd(&hrep[i], c);
    }
}

// ---- kC: every block folds histR (4 reps) + scal (16 slots) + select0, filters ----
__global__ __launch_bounds__(256) void kC(const float4* __restrict__ con4,
                                          const unsigned* __restrict__ histR,
                                          const ScalRep* __restrict__ scal,
                                          unsigned* __restrict__ h1,
                                          GS* __restrict__ G) {
    __shared__ unsigned lh[2048];
    __shared__ unsigned ssum[256];
    __shared__ unsigned sbin, sk;
    __shared__ float    wred[4];
    const int tid = threadIdx.x;

    // fold hist replicas (cross-kernel plain cached loads, L2-hot; 32 KB/block)
    for (int b = tid; b < 2048; b += 256) {
        unsigned c = 0;
#pragma unroll
        for (int r = 0; r < NREP; ++r) c += histR[r * 2048 + b];
        lh[b] = c;
    }
    // fold scalar replicas: uniform loads, identical in every block; pn exact (int)
    unsigned pn = 0;
    float tsl = 0.f, tsc = 0.f;
#pragma unroll
    for (int r = 0; r < NSC; ++r) {
        pn  += scal[r].pn;
        tsl += scal[r].lossl;
        tsc += scal[r].poslc;
    }
    unsigned k0 = 3u * pn;
    if (k0 > (unsigned)M_TOTAL) k0 = (unsigned)M_TOTAL;
    __syncthreads();

    selectk256(lh, 2048, k0, ssum, &sbin, &sk);
    const unsigned b0 = sbin, k1loc = sk;

    const int i = blockIdx.x * 256 + tid;
    float s = 0.f;
    if (i < M4) {
        const float4 q = con4[i];
        const float xs[4] = {q.x, q.y, q.z, q.w};
#pragma unroll
        for (int j = 0; j < 4; ++j) {
            const unsigned u  = __float_as_uint(xs[j]);
            const unsigned hi = u >> 21;
            if (hi > b0) s += xs[j];
            else if (hi == b0) atomicAdd(&h1[(u >> 10) & 0x7FFu], 1u);
        }
    }
#pragma unroll
    for (int off = 1; off < 64; off <<= 1) s += __shfl_xor(s, off);
    if ((tid & 63) == 0) wred[tid >> 6] = s;
    __syncthreads();
    if (tid == 0) {
        const float tot = wred[0] + wred[1] + wred[2] + wred[3];
        if (tot != 0.f) atomicAdd(&G->sumhi0, tot);
        if (blockIdx.x == 0) {
            G->pn = pn; G->lossl = tsl; G->poslc = tsc;
            G->b0 = b0; G->k1 = k1loc;
        }
    }
}

// ---- kD: every block redundantly selects level 1 from h1, then filters ----
__global__ __launch_bounds__(256) void kD(const float4* __restrict__ con4,
                                          const unsigned* __restrict__ h1,
                                          unsigned* __restrict__ h2,
                                          GS* __restrict__ G) {
    __shared__ unsigned lh[2048];
    __shared__ unsigned ssum[256];
    __shared__ unsigned sbin, sk;
    __shared__ float    wred[4];
    const int tid = threadIdx.x;

    for (int b = tid; b < 2048; b += 256) lh[b] = h1[b];   // 8 KB, L2-hot
    __syncthreads();

    const unsigned b0 = G->b0;   // cross-kernel (kC block 0)
    const unsigned k1 = G->k1;
    selectk256(lh, 2048, k1, ssum, &sbin, &sk);
    const unsigned b1 = sbin, k2loc = sk;

    const int i = blockIdx.x * 256 + tid;
    float s = 0.f;
    if (i < M4) {
        const float4 q = con4[i];
        const float xs[4] = {q.x, q.y, q.z, q.w};
#pragma unroll
        for (int j = 0; j < 4; ++j) {
            const unsigned u = __float_as_uint(xs[j]);
            if ((u >> 21) == b0) {
                const unsigned mid = (u >> 10) & 0x7FFu;
                if (mid > b1) s += xs[j];
                else if (mid == b1) atomicAdd(&h2[u & 0x3FFu], 1u);
            }
        }
    }
#pragma unroll
    for (int off = 1; off < 64; off <<= 1) s += __shfl_xor(s, off);
    if ((tid & 63) == 0) wred[tid >> 6] = s;
    __syncthreads();
    if (tid == 0) {
        const float tot = wred[0] + wred[1] + wred[2] + wred[3];
        if (tot != 0.f) atomicAdd(&G->sumhi1, tot);
        if (blockIdx.x == 0) { G->pref = (b0 << 11) | b1; G->k2 = k2loc; }
    }
}

// ---- kE: single tiny block — final select over h2 + output ----
__global__ __launch_bounds__(256) void kE(const unsigned* __restrict__ h2,
                                          const GS* __restrict__ G,
                                          float* __restrict__ out) {
    __shared__ unsigned lh[1024];
    __shared__ unsigned ssum[256];
    __shared__ unsigned sbin, sk;
    __shared__ float    wred[4];
    const int tid = threadIdx.x;

    for (int b = tid; b < 1024; b += 256) lh[b] = h2[b];
    __syncthreads();
    const unsigned pref = G->pref;
    const unsigned k2   = G->k2;
    selectk256(lh, 1024, k2, ssum, &sbin, &sk);
    const unsigned ct = sbin, r = sk;

    float s2 = 0.f;
    for (int b = tid; b < 1024; b += 256) {
        const unsigned c = lh[b];
        if ((unsigned)b > ct && c)
            s2 += (float)c * __uint_as_float((pref << 10) | (unsigned)b);
    }
#pragma unroll
    for (int off = 1; off < 64; off <<= 1) s2 += __shfl_xor(s2, off);
    if ((tid & 63) == 0) wred[tid >> 6] = s2;
    __syncthreads();

    if (tid == 0) {
        const float sumhi2 = wred[0] + wred[1] + wred[2] + wred[3];
        const unsigned pn = G->pn;
        float outv = 0.f;
        if (pn > 0u) {
            const float tval  = __uint_as_float((pref << 10) | ct);
            const float closs = G->poslc + G->sumhi0 + G->sumhi1 + sumhi2 + (float)r * tval;
            outv = (G->lossl + closs) / (float)pn;
        }
        out[0] = outv;
    }
}

extern "C" void kernel_launch(void* const* d_in, const int* in_sizes, int n_in,
                              void* d_out, int out_size, void* d_ws, size_t ws_size,
                              hipStream_t stream) {
    const float* ploc   = (const float*)d_in[0];
    const float* plabel = (const float*)d_in[1];
    const float* gloc   = (const float*)d_in[2];
    const int*   glabel = (const int*)d_in[3];
    float* out = (float*)d_out;
    char*  ws  = (char*)d_ws;

    float*    con   = (float*)(ws + CON_B);
    unsigned* histR = (unsigned*)(ws + HISTR_B);
    unsigned* h1    = (unsigned*)(ws + H1_B);
    unsigned* h2    = (unsigned*)(ws + H2_B);
    GS*       G     = (GS*)(ws + G_B);
    ScalRep*  scal  = (ScalRep*)(ws + SCAL_B);

    hipMemsetAsync(ws + HISTR_B, 0, ZERO_BYTES, stream);   // histR+h1+h2+G+scal (~46 KB)
    kA<<<NBLK_A, 256, 0, stream>>>(ploc, plabel, gloc, glabel, con, histR, scal);
    kC<<<NBLK_S, 256, 0, stream>>>((const float4*)con, histR, scal, h1, G);
    kD<<<NBLK_S, 256, 0, stream>>>((const float4*)con, h1, h2, G);
    kE<<<1, 256, 0, stream>>>(h2, G, out);
}

// Round 10
// 169.529 us; speedup vs baseline: 1.0933x; 1.0024x over previous
//
#include <hip/hip_runtime.h>
#include <math.h>

#define M_TOTAL (32 * 8732)        // 279424 anchors
#define M4      (M_TOTAL / 4)      // 69856 float4
#define NBLK_A  (M_TOTAL / 128)    // 2183 blocks, 128 anchors each, 512 thr
#define NBLK_S  273                // ceil(M4 / 256)
#define NREP    4                  // level-0 hist replication
#define NSC     16                 // scalar-partial replication

// ---- workspace layout (bytes), all 16B-aligned ----
#define CON_B    ((size_t)0)                          // M floats
#define HISTR_B  ((size_t)M_TOTAL * 4)                // NREP*2048 u32
#define H1_B     (HISTR_B + (size_t)NREP * 2048 * 4)  // 2048 u32
#define H2_B     (H1_B + (size_t)2048 * 4)            // 1024 u32
#define G_B      (H2_B + (size_t)1024 * 4)            // GS (128 B reserved)
#define SCAL_B   (G_B + 128)                          // NSC * 64 B replicated scalars
#define ZERO_BYTES ((size_t)NREP * 2048 * 4 + 2048 * 4 + 1024 * 4 + 128 + (size_t)NSC * 64)

struct GS {
    unsigned pn;      // written by kC block 0
    float    lossl;
    float    poslc;
    unsigned b0;
    unsigned k1;
    unsigned pref;    // written by kD block 0: (b0<<11)|b1
    unsigned k2;
    float    sumhi0;  // atomic: sum of con where (u>>21)  > b0
    float    sumhi1;  // atomic: sum where (u>>21)==b0 && mid > b1
};

struct __attribute__((aligned(64))) ScalRep {
    unsigned pn;
    float    lossl;
    float    poslc;
    unsigned pad[13];   // one 64B line per replica
};

__device__ __forceinline__ float smooth_l1(float d) {
    float ad = fabsf(d);
    return (ad < 1.0f) ? 0.5f * ad * ad : ad - 0.5f;
}

#define GLLDS16(gp, lp) __builtin_amdgcn_global_load_lds( \
    (__attribute__((address_space(1))) void*)(gp),        \
    (__attribute__((address_space(3))) void*)(lp), 16, 0, 0)

// 256-thread suffix-select over nbins (multiple of 256): finds bin with
// suffix(bin) >= k > suffix(bin+1); (k==0 -> bin=0,k=0). Verified R3-R9.
__device__ void selectk256(const unsigned* cnt, int nbins, unsigned k,
                           unsigned* ssum, unsigned* pbin, unsigned* pk) {
    const int t = threadIdx.x;
    const int chunk = nbins >> 8;
    if (t == 0) { *pbin = 0u; *pk = 0u; }
    unsigned tot = 0;
    for (int j = 0; j < chunk; ++j) tot += cnt[t * chunk + j];
    ssum[t] = tot;
    __syncthreads();
    for (int off = 1; off < 256; off <<= 1) {
        const unsigned val = ssum[t];
        const unsigned add = (t + off < 256) ? ssum[t + off] : 0u;
        __syncthreads();
        ssum[t] = val + add;
        __syncthreads();
    }
    const unsigned s_after = (t < 255) ? ssum[t + 1] : 0u;
    if (k > 0u && ssum[t] >= k && k > s_after) {
        unsigned cum = s_after;
        for (int j = chunk - 1; j >= 0; --j) {
            const unsigned bin = t * chunk + j;
            const unsigned nc = cum + cnt[bin];
            if (nc >= k) { *pbin = bin; *pk = k - cum; break; }
            cum = nc;
        }
    }
    __syncthreads();
}

// ---- kA: 512-thread LDS-staged CE + smoothL1 + con_neg + hist + scalars ----
// 8 waves/block; each wave stages its 16 rows (5184 B contiguous, 16B-aligned)
// via global_load_lds; 4 lanes per anchor compute logsumexp from LDS.
__global__ __launch_bounds__(512) void kA(const float* __restrict__ ploc,
                                          const float* __restrict__ plabel,
                                          const float* __restrict__ gloc,
                                          const int* __restrict__ glabel,
                                          float* __restrict__ con,
                                          unsigned* __restrict__ histR,
                                          ScalRep* __restrict__ scal) {
    __shared__ __align__(16) float stage[8 * 1296];  // 8 waves * 16 rows * 81 floats
    __shared__ unsigned lh[2048];
    __shared__ float rf[8][3];

    const int tid  = threadIdx.x;
    const int w    = tid >> 6;
    const int lane = tid & 63;
    const int g    = lane >> 2;
    const int l    = lane & 3;

    for (int i = tid; i < 2048; i += 512) lh[i] = 0u;

    const size_t wrow0 = (size_t)blockIdx.x * 128 + (size_t)w * 16;
    const char*  gsrc  = (const char*)(plabel + wrow0 * 81);
    char*        ldst  = (char*)&stage[w * 1296];
#pragma unroll
    for (int j = 0; j < 5; ++j)
        GLLDS16(gsrc + (size_t)j * 1024 + (size_t)lane * 16, ldst + j * 1024);
    if (lane < 4)
        GLLDS16(gsrc + 5120 + (size_t)lane * 16, ldst + 5120);

    const size_t row = wrow0 + g;
    const float pl = ploc[wrow0 * 4 + lane];
    const float gl = gloc[wrow0 * 4 + lane];
    int gt = 0;
    if (l == 0) gt = glabel[row];
    const int mask = gt > 0;

    float s = smooth_l1(pl - gl);
    s += __shfl_xor(s, 1);
    s += __shfl_xor(s, 2);

    __syncthreads();   // drains global_load_lds (vmcnt) + lh zero visible

    const float* rowp = &stage[w * 1296 + g * 81];
    float v[20];
    float m = -INFINITY;
#pragma unroll
    for (int j = 0; j < 20; ++j) { v[j] = rowp[j * 4 + l]; m = fmaxf(m, v[j]); }
    float v80 = 0.0f;
    if (l == 0) { v80 = rowp[80]; m = fmaxf(m, v80); }
    m = fmaxf(m, __shfl_xor(m, 1));
    m = fmaxf(m, __shfl_xor(m, 2));

    float e = 0.0f;
#pragma unroll
    for (int j = 0; j < 20; ++j) e += __expf(v[j] - m);
    if (l == 0) e += __expf(v80 - m);
    e += __shfl_xor(e, 1);
    e += __shfl_xor(e, 2);
    const float lse = m + __logf(e);

    float wl = 0.f, wc = 0.f, wp = 0.f;
    if (l == 0) {
        const float x_gt   = rowp[gt];
        const float loss_c = lse - x_gt;
        const float cn     = mask ? 0.0f : fmaxf(loss_c, 0.0f);
        con[row] = cn;
        atomicAdd(&lh[__float_as_uint(cn) >> 21], 1u);   // LDS atomic, cheap
        if (mask) { wl = s; wc = loss_c; wp = 1.0f; }
    }
#pragma unroll
    for (int off = 4; off < 64; off <<= 1) {
        wl += __shfl_xor(wl, off);
        wc += __shfl_xor(wc, off);
        wp += __shfl_xor(wp, off);
    }
    if (lane == 0) { rf[w][0] = wl; rf[w][1] = wc; rf[w][2] = wp; }
    __syncthreads();   // lh atomics done; rf visible

    if (tid == 0) {
        float bl = 0.f, bc = 0.f, bpf = 0.f;
#pragma unroll
        for (int i = 0; i < 8; ++i) { bl += rf[i][0]; bc += rf[i][1]; bpf += rf[i][2]; }
        const unsigned bp = (unsigned)(bpf + 0.5f);
        ScalRep* sr = &scal[blockIdx.x & (NSC - 1)];
        if (bp) {
            atomicAdd(&sr->pn, bp);
            atomicAdd(&sr->lossl, bl);
            atomicAdd(&sr->poslc, bc);
        }
    }

    // merge private hist into replicated global hist (~13 nonzero bins/block)
    unsigned* hrep = histR + (size_t)(blockIdx.x & (NREP - 1)) * 2048;
    for (int i = tid; i < 2048; i += 512) {
        const unsigned c = lh[i];
        if (c) atomicAdd(&hrep[i], c);
    }
}

// ---- kC: every block folds histR (4 reps) + scal (16 slots) + select0, filters ----
__global__ __launch_bounds__(256) void kC(const float4* __restrict__ con4,
                                          const unsigned* __restrict__ histR,
                                          const ScalRep* __restrict__ scal,
                                          unsigned* __restrict__ h1,
                                          GS* __restrict__ G) {
    __shared__ unsigned lh[2048];
    __shared__ unsigned ssum[256];
    __shared__ unsigned sbin, sk;
    __shared__ float    wred[4];
    const int tid = threadIdx.x;

    for (int b = tid; b < 2048; b += 256) {
        unsigned c = 0;
#pragma unroll
        for (int r = 0; r < NREP; ++r) c += histR[r * 2048 + b];
        lh[b] = c;
    }
    unsigned pn = 0;
    float tsl = 0.f, tsc = 0.f;
#pragma unroll
    for (int r = 0; r < NSC; ++r) {
        pn  += scal[r].pn;
        tsl += scal[r].lossl;
        tsc += scal[r].poslc;
    }
    unsigned k0 = 3u * pn;
    if (k0 > (unsigned)M_TOTAL) k0 = (unsigned)M_TOTAL;
    __syncthreads();

    selectk256(lh, 2048, k0, ssum, &sbin, &sk);
    const unsigned b0 = sbin, k1loc = sk;

    const int i = blockIdx.x * 256 + tid;
    float s = 0.f;
    if (i < M4) {
        const float4 q = con4[i];
        const float xs[4] = {q.x, q.y, q.z, q.w};
#pragma unroll
        for (int j = 0; j < 4; ++j) {
            const unsigned u  = __float_as_uint(xs[j]);
            const unsigned hi = u >> 21;
            if (hi > b0) s += xs[j];
            else if (hi == b0) atomicAdd(&h1[(u >> 10) & 0x7FFu], 1u);
        }
    }
#pragma unroll
    for (int off = 1; off < 64; off <<= 1) s += __shfl_xor(s, off);
    if ((tid & 63) == 0) wred[tid >> 6] = s;
    __syncthreads();
    if (tid == 0) {
        const float tot = wred[0] + wred[1] + wred[2] + wred[3];
        if (tot != 0.f) atomicAdd(&G->sumhi0, tot);
        if (blockIdx.x == 0) {
            G->pn = pn; G->lossl = tsl; G->poslc = tsc;
            G->b0 = b0; G->k1 = k1loc;
        }
    }
}

// ---- kD: every block redundantly selects level 1 from h1, then filters ----
__global__ __launch_bounds__(256) void kD(const float4* __restrict__ con4,
                                          const unsigned* __restrict__ h1,
                                          unsigned* __restrict__ h2,
                                          GS* __restrict__ G) {
    __shared__ unsigned lh[2048];
    __shared__ unsigned ssum[256];
    __shared__ unsigned sbin, sk;
    __shared__ float    wred[4];
    const int tid = threadIdx.x;

    for (int b = tid; b < 2048; b += 256) lh[b] = h1[b];   // 8 KB, L2-hot
    __syncthreads();

    const unsigned b0 = G->b0;
    const unsigned k1 = G->k1;
    selectk256(lh, 2048, k1, ssum, &sbin, &sk);
    const unsigned b1 = sbin, k2loc = sk;

    const int i = blockIdx.x * 256 + tid;
    float s = 0.f;
    if (i < M4) {
        const float4 q = con4[i];
        const float xs[4] = {q.x, q.y, q.z, q.w};
#pragma unroll
        for (int j = 0; j < 4; ++j) {
            const unsigned u = __float_as_uint(xs[j]);
            if ((u >> 21) == b0) {
                const unsigned mid = (u >> 10) & 0x7FFu;
                if (mid > b1) s += xs[j];
                else if (mid == b1) atomicAdd(&h2[u & 0x3FFu], 1u);
            }
        }
    }
#pragma unroll
    for (int off = 1; off < 64; off <<= 1) s += __shfl_xor(s, off);
    if ((tid & 63) == 0) wred[tid >> 6] = s;
    __syncthreads();
    if (tid == 0) {
        const float tot = wred[0] + wred[1] + wred[2] + wred[3];
        if (tot != 0.f) atomicAdd(&G->sumhi1, tot);
        if (blockIdx.x == 0) { G->pref = (b0 << 11) | b1; G->k2 = k2loc; }
    }
}

// ---- kE: single tiny block — final select over h2 + output ----
__global__ __launch_bounds__(256) void kE(const unsigned* __restrict__ h2,
                                          const GS* __restrict__ G,
                                          float* __restrict__ out) {
    __shared__ unsigned lh[1024];
    __shared__ unsigned ssum[256];
    __shared__ unsigned sbin, sk;
    __shared__ float    wred[4];
    const int tid = threadIdx.x;

    for (int b = tid; b < 1024; b += 256) lh[b] = h2[b];
    __syncthreads();
    const unsigned pref = G->pref;
    const unsigned k2   = G->k2;
    selectk256(lh, 1024, k2, ssum, &sbin, &sk);
    const unsigned ct = sbin, r = sk;

    float s2 = 0.f;
    for (int b = tid; b < 1024; b += 256) {
        const unsigned c = lh[b];
        if ((unsigned)b > ct && c)
            s2 += (float)c * __uint_as_float((pref << 10) | (unsigned)b);
    }
#pragma unroll
    for (int off = 1; off < 64; off <<= 1) s2 += __shfl_xor(s2, off);
    if ((tid & 63) == 0) wred[tid >> 6] = s2;
    __syncthreads();

    if (tid == 0) {
        const float sumhi2 = wred[0] + wred[1] + wred[2] + wred[3];
        const unsigned pn = G->pn;
        float outv = 0.f;
        if (pn > 0u) {
            const float tval  = __uint_as_float((pref << 10) | ct);
            const float closs = G->poslc + G->sumhi0 + G->sumhi1 + sumhi2 + (float)r * tval;
            outv = (G->lossl + closs) / (float)pn;
        }
        out[0] = outv;
    }
}

extern "C" void kernel_launch(void* const* d_in, const int* in_sizes, int n_in,
                              void* d_out, int out_size, void* d_ws, size_t ws_size,
                              hipStream_t stream) {
    const float* ploc   = (const float*)d_in[0];
    const float* plabel = (const float*)d_in[1];
    const float* gloc   = (const float*)d_in[2];
    const int*   glabel = (const int*)d_in[3];
    float* out = (float*)d_out;
    char*  ws  = (char*)d_ws;

    float*    con   = (float*)(ws + CON_B);
    unsigned* histR = (unsigned*)(ws + HISTR_B);
    unsigned* h1    = (unsigned*)(ws + H1_B);
    unsigned* h2    = (unsigned*)(ws + H2_B);
    GS*       G     = (GS*)(ws + G_B);
    ScalRep*  scal  = (ScalRep*)(ws + SCAL_B);

    hipMemsetAsync(ws + HISTR_B, 0, ZERO_BYTES, stream);   // histR+h1+h2+G+scal (~46 KB)
    kA<<<NBLK_A, 512, 0, stream>>>(ploc, plabel, gloc, glabel, con, histR, scal);
    kC<<<NBLK_S, 256, 0, stream>>>((const float4*)con, histR, scal, h1, G);
    kD<<<NBLK_S, 256, 0, stream>>>((const float4*)con, h1, h2, G);
    kE<<<1, 256, 0, stream>>>(h2, G, out);
}